// Round 2
// baseline (904.734 us; speedup 1.0000x reference)
//
#include <hip/hip_runtime.h>
#include <math.h>

#define NTOT   8192      // B*H*W rows
#define KCODES 8192
#define CDIM   256
#define HWSZ   1024
#define NSEG   2
#define KSEG   (KCODES / NSEG)   // 4096
#define TM     32                // rows per block
#define TN     128               // codes per k-tile
#define KC     32                // c-chunk
#define XS_STRIDE 260            // floats (65 float4 slots)
#define ES_STRIDE 36             // floats (9 float4 slots; slot step 9 odd -> 2-way free)

#define QOFF   ((size_t)NTOT * CDIM)   // 2097152: loss at QOFF, indices at QOFF+1

// ---------------- fused score GEMM + argmin ----------------
// Reference (numpy fp32): d = round( round(x2 - 2*dot) + e2 ). Since x2 ~ 256
// and e2 < half-ulp(d), d == round(x2 - 2*dot) bitwise. We replicate exactly:
// x2 via numpy pairwise-summation order, score via single-rounding fmaf.
__global__ __launch_bounds__(256) void vq_argmin_kernel(
    const float* __restrict__ z, const float* __restrict__ emb,
    float* __restrict__ pV, int* __restrict__ pI) {
  __shared__ float xs[TM * XS_STRIDE];   // 33280 B
  __shared__ float es[TN * ES_STRIDE];   // 18432 B
  __shared__ float x2s[TM];
  int tid = threadIdx.x;
  int rowblk = blockIdx.x;      // 0..255
  int seg = blockIdx.y;         // 0..1
  int n0 = rowblk * TM;
  int b = n0 >> 10;             // TM divides 1024 -> single b per block
  int hw0 = n0 & 1023;
  const float* zb = z + (size_t)b * (CDIM * HWSZ) + hw0;

  // stage x tile: xs[r][c] = z[b, c, hw0+r]; coalesced over r (32-wide)
  {
    int r = tid & 31;
    int cbase = tid >> 5;          // 0..7
    for (int it = 0; it < 32; ++it) {
      int c = cbase + it * 8;
      xs[r * XS_STRIDE + c] = zb[(size_t)c * HWSZ + r];
    }
  }
  __syncthreads();

  // x2[r] with numpy's exact pairwise order: 256 = 128+128, each 128 via
  // 8 accumulators; squares rounded individually; NO fp contraction.
  if (tid < TM) {
#pragma clang fp contract(off)
    const float* xr = &xs[tid * XS_STRIDE];
    float r0[8], r1[8];
#pragma unroll
    for (int j = 0; j < 8; ++j) {
      float v = xr[j];       r0[j] = v * v;
      float w = xr[128 + j]; r1[j] = w * w;
    }
    for (int i = 8; i < 128; i += 8) {
#pragma unroll
      for (int j = 0; j < 8; ++j) {
        float v = xr[i + j];       float a  = v * v; r0[j] = r0[j] + a;
        float w = xr[128 + i + j]; float b2 = w * w; r1[j] = r1[j] + b2;
      }
    }
    float lo = ((r0[0] + r0[1]) + (r0[2] + r0[3])) + ((r0[4] + r0[5]) + (r0[6] + r0[7]));
    float hi = ((r1[0] + r1[1]) + (r1[2] + r1[3])) + ((r1[4] + r1[5]) + (r1[6] + r1[7]));
    x2s[tid] = lo + hi;
  }
  __syncthreads();

  int tc = tid & 15;       // code lane: k = tc + 16*j
  int tr = tid >> 4;       // row lane:  r = tr + 16*i
  float x2r[2];
  x2r[0] = x2s[tr];
  x2r[1] = x2s[tr + 16];
  float best[2];
  int bidx[2];
  best[0] = INFINITY; best[1] = INFINITY;
  bidx[0] = 0; bidx[1] = 0;
  int kbase = seg * KSEG;

  for (int kt = 0; kt < KSEG / TN; ++kt) {   // 32 k-tiles
    float acc[2][8];
#pragma unroll
    for (int i = 0; i < 2; ++i)
#pragma unroll
      for (int j = 0; j < 8; ++j) acc[i][j] = 0.f;

    for (int ct = 0; ct < CDIM / KC; ++ct) { // 8 c-chunks
      __syncthreads();
      { // stage es[128][32]: 4096 floats, 16/thread
        int ko = tid >> 1;              // 0..127
        int co = (tid & 1) * 16;        // 0 or 16
        const float* src = emb + (size_t)(kbase + kt * TN + ko) * CDIM + ct * KC + co;
        float4 v0 = *(const float4*)(src);
        float4 v1 = *(const float4*)(src + 4);
        float4 v2 = *(const float4*)(src + 8);
        float4 v3 = *(const float4*)(src + 12);
        float* dst = &es[ko * ES_STRIDE + co];
        *(float4*)(dst)      = v0;
        *(float4*)(dst + 4)  = v1;
        *(float4*)(dst + 8)  = v2;
        *(float4*)(dst + 12) = v3;
      }
      __syncthreads();
      const float4* xs4 = (const float4*)xs;
      const float4* es4 = (const float4*)es;
#pragma unroll
      for (int c4 = 0; c4 < KC / 4; ++c4) {
        float4 a[2], bb[8];
#pragma unroll
        for (int i = 0; i < 2; ++i)
          a[i] = xs4[(tr + 16 * i) * (XS_STRIDE / 4) + ct * (KC / 4) + c4];
#pragma unroll
        for (int j = 0; j < 8; ++j)
          bb[j] = es4[(tc + 16 * j) * (ES_STRIDE / 4) + c4];
#pragma unroll
        for (int i = 0; i < 2; ++i)
#pragma unroll
          for (int j = 0; j < 8; ++j) {
            acc[i][j] = fmaf(a[i].x, bb[j].x, acc[i][j]);
            acc[i][j] = fmaf(a[i].y, bb[j].y, acc[i][j]);
            acc[i][j] = fmaf(a[i].z, bb[j].z, acc[i][j]);
            acc[i][j] = fmaf(a[i].w, bb[j].w, acc[i][j]);
          }
      }
    }
    // score + running argmin (ascending k within thread -> strict < keeps first)
#pragma unroll
    for (int j = 0; j < 8; ++j) {
      int k = kbase + kt * TN + tc + 16 * j;
#pragma unroll
      for (int i = 0; i < 2; ++i) {
        float s = fmaf(-2.f, acc[i][j], x2r[i]);  // single rounding == np's x2 - 2.0*dot
        if (s < best[i]) { best[i] = s; bidx[i] = k; }
      }
    }
  }

  // cross-thread (tc) reduction per row, reusing es space
  __syncthreads();
  float* redV = es;                       // [TM][16]
  int*   redI = (int*)(es + TM * 16);     // [TM][16]
#pragma unroll
  for (int i = 0; i < 2; ++i) {
    redV[(tr + 16 * i) * 16 + tc] = best[i];
    redI[(tr + 16 * i) * 16 + tc] = bidx[i];
  }
  __syncthreads();
  if (tid < TM) {
    float bv = INFINITY; int bi = 0x7fffffff;
    for (int t2 = 0; t2 < 16; ++t2) {
      float v = redV[tid * 16 + t2];
      int id  = redI[tid * 16 + t2];
      if (v < bv || (v == bv && id < bi)) { bv = v; bi = id; }
    }
    pV[(size_t)seg * NTOT + n0 + tid] = bv;
    pI[(size_t)seg * NTOT + n0 + tid] = bi;
  }
}

// ---------------- merge segments, gather quantized, loss partials ----------------
__global__ __launch_bounds__(256) void gather_kernel(
    const float* __restrict__ z, const float* __restrict__ emb,
    const float* __restrict__ pV, const int* __restrict__ pI,
    float* __restrict__ out, float* __restrict__ lossPart) {
  __shared__ int sidx[64];
  __shared__ float swsum[4];
  int tid = threadIdx.x;
  int bid = blockIdx.x;            // 0..127
  int n0 = bid * 64;
  if (tid < 64) {
    int n = n0 + tid;
    float bv = pV[n]; int bi = pI[n];
    for (int s = 1; s < NSEG; ++s) {
      float v = pV[(size_t)s * NTOT + n];
      int id  = pI[(size_t)s * NTOT + n];
      if (v < bv) { bv = v; bi = id; }   // tie keeps lower segment = lower index
    }
    sidx[tid] = bi;
    out[QOFF + 1 + n] = (float)bi;       // indices output (as f32)
  }
  __syncthreads();
  int lane = tid & 63;
  int cw = tid >> 6;                     // wave id 0..3
  int b = n0 >> 10;
  int hw = (n0 & 1023) + lane;
  const float* erow = emb + (size_t)sidx[lane] * CDIM;
  float lacc = 0.f;
  for (int ci = 0; ci < 64; ++ci) {
    int c = cw * 64 + ci;
    float q = erow[c];
    size_t o = (size_t)b * (CDIM * HWSZ) + (size_t)c * HWSZ + hw;
    float zv = z[o];
    out[o] = q;                           // coalesced over hw
    float d = q - zv;
    lacc += d * d;
  }
#pragma unroll
  for (int off = 32; off > 0; off >>= 1) lacc += __shfl_down(lacc, off, 64);
  if (lane == 0) swsum[cw] = lacc;
  __syncthreads();
  if (tid == 0) lossPart[bid] = swsum[0] + swsum[1] + swsum[2] + swsum[3];
}

__global__ void loss_kernel(const float* __restrict__ lossPart, float* __restrict__ out) {
  if (threadIdx.x == 0) {
    double s = 0.0;
    for (int i = 0; i < 128; ++i) s += (double)lossPart[i];
    // codebook_loss + 0.25*commitment_loss = 1.25 * mean((q - z)^2)
    out[QOFF] = (float)(s * 1.25 / (double)(NTOT * CDIM));
  }
}

extern "C" void kernel_launch(void* const* d_in, const int* in_sizes, int n_in,
                              void* d_out, int out_size, void* d_ws, size_t ws_size,
                              hipStream_t stream) {
  const float* z   = (const float*)d_in[0];
  const float* emb = (const float*)d_in[1];
  float* out = (float*)d_out;
  float* ws  = (float*)d_ws;
  float* pV       = ws;                          // NSEG*8192
  int*   pI       = (int*)(ws + NSEG * NTOT);    // NSEG*8192
  float* lossPart = ws + 2 * NSEG * NTOT;        // 128

  hipLaunchKernelGGL(vq_argmin_kernel, dim3(NTOT / TM, NSEG), dim3(256), 0, stream,
                     z, emb, pV, pI);
  hipLaunchKernelGGL(gather_kernel, dim3(NTOT / 64), dim3(256), 0, stream,
                     z, emb, pV, pI, out, lossPart);
  hipLaunchKernelGGL(loss_kernel, dim3(1), dim3(64), 0, stream, lossPart, out);
}

// Round 5
// 582.262 us; speedup vs baseline: 1.5538x; 1.5538x over previous
//
#include <hip/hip_runtime.h>
#include <hip/hip_bf16.h>
#include <math.h>

#define NROW   8192      // B*H*W z-rows
#define KCODE  8192      // codebook entries
#define CD     256
#define HWSZ   1024
#define BK     32        // K per MFMA step
#define NKSTEP (CD / BK) // 8
#define NBLK   (KCODE / 128)   // 64 code blocks
#define MARGIN 7.5e-5f

#define QOFF   ((size_t)NROW * CD)   // 2097152: loss at QOFF, indices at QOFF+1

typedef __attribute__((ext_vector_type(8))) short short8;
typedef __attribute__((ext_vector_type(4))) float f32x4;
typedef unsigned long long u64;

typedef const __attribute__((address_space(1))) unsigned int* as1_cu32;
typedef __attribute__((address_space(3))) unsigned int* as3_u32;

__device__ __forceinline__ void gload16(const void* g, void* l) {
  // global -> LDS direct; LDS dest = wave-uniform base + lane*16.
  // addrspacecast generic->AS1/AS3 (canonical lowering extracts LDS offset)
  __builtin_amdgcn_global_load_lds((as1_cu32)g, (as3_u32)l, 16, 0, 0);
}

// sortable key: high32 = monotone float map, low32 = code (lex tie -> low index)
__device__ __forceinline__ u64 makeKey(float v, int code) {
  unsigned u = __float_as_uint(v);
  unsigned m = (u & 0x80000000u) ? ~u : (u | 0x80000000u);
  return ((u64)m << 32) | (unsigned)code;
}
__device__ __forceinline__ float keyVal(u64 k) {
  unsigned m = (unsigned)(k >> 32);
  unsigned u = (m & 0x80000000u) ? (m ^ 0x80000000u) : ~m;
  return __uint_as_float(u);
}
__device__ __forceinline__ void ins3(u64 k, u64& t1, u64& t2, u64& t3) {
  if (k < t1) { t3 = t2; t2 = t1; t1 = k; }
  else if (k < t2) { t3 = t2; t2 = k; }
  else if (k < t3) { t3 = k; }
}

// ---------------- k1: z -> Xhi bf16 [n][c] + exact-numpy x2 (R2-proven) ----------------
__global__ __launch_bounds__(256) void splitz_x2_kernel(
    const float* __restrict__ z, unsigned short* __restrict__ Xhi,
    float* __restrict__ x2g) {
  __shared__ float xs[32 * 260];
  int tid = threadIdx.x;
  int n0 = blockIdx.x * 32;
  int b = n0 >> 10;
  int hw0 = n0 & 1023;
  const float* zb = z + (size_t)b * (CD * HWSZ) + hw0;
  {
    int r = tid & 31;
    int cbase = tid >> 5;
    for (int it = 0; it < 32; ++it) {
      int c = cbase + it * 8;
      xs[r * 260 + c] = zb[(size_t)c * HWSZ + r];
    }
  }
  __syncthreads();
  if (tid < 32) {
#pragma clang fp contract(off)
    const float* xr = &xs[tid * 260];
    float r0[8], r1[8];
#pragma unroll
    for (int j = 0; j < 8; ++j) {
      float v = xr[j];       r0[j] = v * v;
      float w = xr[128 + j]; r1[j] = w * w;
    }
    for (int i = 8; i < 128; i += 8) {
#pragma unroll
      for (int j = 0; j < 8; ++j) {
        float v = xr[i + j];       float a  = v * v; r0[j] = r0[j] + a;
        float w = xr[128 + i + j]; float b2 = w * w; r1[j] = r1[j] + b2;
      }
    }
    float lo = ((r0[0] + r0[1]) + (r0[2] + r0[3])) + ((r0[4] + r0[5]) + (r0[6] + r0[7]));
    float hi = ((r1[0] + r1[1]) + (r1[2] + r1[3])) + ((r1[4] + r1[5]) + (r1[6] + r1[7]));
    x2g[n0 + tid] = lo + hi;
  }
  for (int r = 0; r < 32; ++r) {
    float v = xs[r * 260 + tid];
    __hip_bfloat16 h = __float2bfloat16(v);
    Xhi[(size_t)(n0 + r) * CD + tid] = *(unsigned short*)&h;
  }
}

// ---------------- k2: emb -> Ehi bf16 [k][c] ----------------
__global__ __launch_bounds__(256) void splite_kernel(
    const float* __restrict__ emb, unsigned short* __restrict__ Ehi) {
  int n = blockIdx.x * 256 + threadIdx.x;
  __hip_bfloat16 h = __float2bfloat16(emb[n]);
  Ehi[n] = *(unsigned short*)&h;
}

// ---------------- k3: bf16 MFMA GEMM, per-(row, 128-code-block) top-3 ----------------
__global__ __launch_bounds__(256) void gemm_top3_kernel(
    const unsigned short* __restrict__ Eg,   // A [8192][256] bf16
    const unsigned short* __restrict__ Xg,   // B [8192][256] bf16
    u64* __restrict__ pK1, u64* __restrict__ pK2, u64* __restrict__ pK3) {
  __shared__ unsigned short As[128 * BK];   // 8 KB [code][k]
  __shared__ unsigned short Bs[128 * BK];   // 8 KB [zrow][k]
  __shared__ u64 redK[2][128][3];           // 6 KB

  int tid = threadIdx.x;
  int cb0 = blockIdx.x * 128;   // code tile
  int rb0 = blockIdx.y * 128;   // zrow tile
  int wid = tid >> 6, lane = tid & 63;
  int llo = lane & 15, lhi = lane >> 4;
  int wr = wid & 1, wc = wid >> 1;

  f32x4 acc[4][4];
#pragma unroll
  for (int i = 0; i < 4; ++i)
#pragma unroll
    for (int j = 0; j < 4; ++j) acc[i][j] = (f32x4){0.f, 0.f, 0.f, 0.f};

  int srow = tid >> 2;                 // 0..63
  int schunk = (tid & 3) * 16;         // byte chunk within 64B k-slab
  const char* gA = (const char*)Eg + ((size_t)(cb0 + srow)) * 512 + schunk;
  const char* gB = (const char*)Xg + ((size_t)(rb0 + srow)) * 512 + schunk;
  char* AsB = (char*)As + wid * 1024;
  char* BsB = (char*)Bs + wid * 1024;

  for (int ks = 0; ks < NKSTEP; ++ks) {
    int kb = ks * 64;   // BK bf16 = 64 B
    gload16(gA + kb, AsB);
    gload16(gA + (size_t)64 * 512 + kb, AsB + 4096);
    gload16(gB + kb, BsB);
    gload16(gB + (size_t)64 * 512 + kb, BsB + 4096);
    __syncthreads();   // drains vmcnt

    short8 af[4], bf[4];
    // wave quadrant offsets (wr/wc) — THE R3/R4 BUG: these were missing
#pragma unroll
    for (int i = 0; i < 4; ++i)
      af[i] = *(const short8*)((const char*)As + (64 * wr + 16 * i + llo) * 64 + lhi * 16);
#pragma unroll
    for (int j = 0; j < 4; ++j)
      bf[j] = *(const short8*)((const char*)Bs + (64 * wc + 16 * j + llo) * 64 + lhi * 16);
#pragma unroll
    for (int i = 0; i < 4; ++i)
#pragma unroll
      for (int j = 0; j < 4; ++j)
        acc[i][j] = __builtin_amdgcn_mfma_f32_16x16x32_bf16(af[i], bf[j], acc[i][j], 0, 0, 0);
    __syncthreads();
  }

  // epilogue: v = -2*dot (x2 cancels per-row; monotone), top-3 per row.
  // C/D: col(zrow)=lane&15, row(code)=4*lhi+r4 (m89-verified)
#pragma unroll
  for (int j = 0; j < 4; ++j) {
    u64 t1 = ~0ull, t2 = ~0ull, t3 = ~0ull;
#pragma unroll
    for (int i = 0; i < 4; ++i)
#pragma unroll
      for (int r4 = 0; r4 < 4; ++r4) {
        float v = -2.0f * acc[i][j][r4];
        int code = cb0 + 64 * wr + 16 * i + 4 * lhi + r4;
        ins3(makeKey(v, code), t1, t2, t3);
      }
#pragma unroll
    for (int off = 16; off < 64; off <<= 1) {
      u64 o1 = __shfl_xor(t1, off, 64);
      u64 o2 = __shfl_xor(t2, off, 64);
      u64 o3 = __shfl_xor(t3, off, 64);
      ins3(o1, t1, t2, t3); ins3(o2, t1, t2, t3); ins3(o3, t1, t2, t3);
    }
    if (lhi == 0) {
      int zl = 64 * wc + 16 * j + llo;
      redK[wr][zl][0] = t1; redK[wr][zl][1] = t2; redK[wr][zl][2] = t3;
    }
  }
  __syncthreads();
  if (tid < 128) {
    u64 t1 = redK[0][tid][0], t2 = redK[0][tid][1], t3 = redK[0][tid][2];
    ins3(redK[1][tid][0], t1, t2, t3);
    ins3(redK[1][tid][1], t1, t2, t3);
    ins3(redK[1][tid][2], t1, t2, t3);
    size_t o = (size_t)blockIdx.x * NROW + rb0 + tid;
    pK1[o] = t1; pK2[o] = t2; pK3[o] = t3;
  }
}

// ---------------- k4: merge blocks + exact re-rank (R2 semantics) ----------------
__global__ __launch_bounds__(256) void merge_rerank_kernel(
    const float* __restrict__ z, const float* __restrict__ emb,
    const u64* __restrict__ pK1, const u64* __restrict__ pK2,
    const u64* __restrict__ pK3, const float* __restrict__ x2g,
    int* __restrict__ idx, float* __restrict__ out) {
  int n = blockIdx.x * 256 + threadIdx.x;
  u64 kmin = ~0ull;
  for (int blk = 0; blk < NBLK; ++blk) {
    u64 k = pK1[(size_t)blk * NROW + n];
    if (k < kmin) kmin = k;
  }
  float vcut = keyVal(kmin) + MARGIN;
  int cand[8]; int nc = 0;
  for (int blk = 0; blk < NBLK; ++blk) {
    size_t o = (size_t)blk * NROW + n;
    u64 k1 = pK1[o], k2 = pK2[o], k3 = pK3[o];
    if (keyVal(k1) <= vcut && nc < 8) cand[nc++] = (int)(k1 & 0xffffffffu);
    if (keyVal(k2) <= vcut && nc < 8) cand[nc++] = (int)(k2 & 0xffffffffu);
    if (keyVal(k3) <= vcut && nc < 8) cand[nc++] = (int)(k3 & 0xffffffffu);
  }
  int b = n >> 10, hw = n & 1023;
  const float* zp = z + (size_t)b * (CD * HWSZ) + hw;
  float x2 = x2g[n];
  float bs = INFINITY; int bi = 0x7fffffff;
  for (int c0 = 0; c0 < nc; ++c0) {
    int k = cand[c0];
    const float* ep = emb + (size_t)k * CD;
    float acc = 0.f;
    for (int c = 0; c < CD; ++c)                 // sequential fmaf chain == R2 dot
      acc = fmaf(zp[(size_t)c * HWSZ], ep[c], acc);
    float s = fmaf(-2.f, acc, x2);               // single rounding == np grid
    if (s < bs || (s == bs && k < bi)) { bs = s; bi = k; }
  }
  idx[n] = bi;
  out[QOFF + 1 + n] = (float)bi;
}

// ---------------- k5: gather quantized + loss partials (R2-proven) ----------------
__global__ __launch_bounds__(256) void gather_kernel(
    const float* __restrict__ z, const float* __restrict__ emb,
    const int* __restrict__ idx, float* __restrict__ out,
    float* __restrict__ lossPart) {
  __shared__ int sidx[64];
  __shared__ float swsum[4];
  int tid = threadIdx.x;
  int bid = blockIdx.x;
  int n0 = bid * 64;
  if (tid < 64) sidx[tid] = idx[n0 + tid];
  __syncthreads();
  int lane = tid & 63;
  int cw = tid >> 6;
  int b = n0 >> 10;
  int hw = (n0 & 1023) + lane;
  const float* erow = emb + (size_t)sidx[lane] * CD;
  float lacc = 0.f;
  for (int ci = 0; ci < 64; ++ci) {
    int c = cw * 64 + ci;
    float q = erow[c];
    size_t o = (size_t)b * (CD * HWSZ) + (size_t)c * HWSZ + hw;
    float zv = z[o];
    out[o] = q;
    float d = q - zv;
    lacc += d * d;
  }
#pragma unroll
  for (int off = 32; off > 0; off >>= 1) lacc += __shfl_down(lacc, off, 64);
  if (lane == 0) swsum[cw] = lacc;
  __syncthreads();
  if (tid == 0) lossPart[bid] = swsum[0] + swsum[1] + swsum[2] + swsum[3];
}

__global__ void loss_kernel(const float* __restrict__ lossPart, float* __restrict__ out) {
  if (threadIdx.x == 0) {
    double s = 0.0;
    for (int i = 0; i < 128; ++i) s += (double)lossPart[i];
    out[QOFF] = (float)(s * 1.25 / (double)(NROW * CD));
  }
}

extern "C" void kernel_launch(void* const* d_in, const int* in_sizes, int n_in,
                              void* d_out, int out_size, void* d_ws, size_t ws_size,
                              hipStream_t stream) {
  const float* z   = (const float*)d_in[0];
  const float* emb = (const float*)d_in[1];
  float* out = (float*)d_out;

  // bf16 operands live in d_out's 8MB quantized region (overwritten by gather later)
  unsigned short* Ehi = (unsigned short*)d_out;                       // 4 MB
  unsigned short* Xhi = (unsigned short*)d_out + (size_t)KCODE * CD;  // 4 MB

  // ws: pK1|pK2|pK3 (3 x 4 MB) | x2 | idx | lossPart  -> ~12.07 MB total
  u64* pK1 = (u64*)d_ws;
  u64* pK2 = pK1 + (size_t)NBLK * NROW;
  u64* pK3 = pK2 + (size_t)NBLK * NROW;
  float* x2g = (float*)(pK3 + (size_t)NBLK * NROW);
  int* idx = (int*)(x2g + NROW);
  float* lossPart = (float*)(idx + NROW);

  hipLaunchKernelGGL(splitz_x2_kernel, dim3(NROW / 32), dim3(256), 0, stream, z, Xhi, x2g);
  hipLaunchKernelGGL(splite_kernel, dim3((KCODE * CD) / 256), dim3(256), 0, stream, emb, Ehi);
  hipLaunchKernelGGL(gemm_top3_kernel, dim3(KCODE / 128, NROW / 128), dim3(256), 0, stream,
                     Ehi, Xhi, pK1, pK2, pK3);
  hipLaunchKernelGGL(merge_rerank_kernel, dim3(NROW / 256), dim3(256), 0, stream,
                     z, emb, pK1, pK2, pK3, x2g, idx, out);
  hipLaunchKernelGGL(gather_kernel, dim3(NROW / 64), dim3(256), 0, stream,
                     z, emb, idx, out, lossPart);
  hipLaunchKernelGGL(loss_kernel, dim3(1), dim3(64), 0, stream, lossPart, out);
}

// Round 6
// 579.824 us; speedup vs baseline: 1.5604x; 1.0042x over previous
//
#include <hip/hip_runtime.h>
#include <hip/hip_bf16.h>
#include <math.h>

#define NROW   8192      // B*H*W z-rows
#define KCODE  8192      // codebook entries
#define CD     256
#define HWSZ   1024
#define BK     32        // K per MFMA step
#define NKSTEP (CD / BK) // 8
#define NBLK   (KCODE / 128)   // 64 code blocks
#define MARGIN 7.5e-5f

#define QOFF   ((size_t)NROW * CD)   // 2097152: loss at QOFF, indices at QOFF+1

typedef __attribute__((ext_vector_type(8))) short short8;
typedef __attribute__((ext_vector_type(4))) float f32x4;
typedef unsigned long long u64;

// sortable key: high32 = monotone float map, low32 = code (lex tie -> low index)
__device__ __forceinline__ u64 makeKey(float v, int code) {
  unsigned u = __float_as_uint(v);
  unsigned m = (u & 0x80000000u) ? ~u : (u | 0x80000000u);
  return ((u64)m << 32) | (unsigned)code;
}
__device__ __forceinline__ float keyVal(u64 k) {
  unsigned m = (unsigned)(k >> 32);
  unsigned u = (m & 0x80000000u) ? (m ^ 0x80000000u) : ~m;
  return __uint_as_float(u);
}
__device__ __forceinline__ void ins3(u64 k, u64& t1, u64& t2, u64& t3) {
  if (k < t1) { t3 = t2; t2 = t1; t1 = k; }
  else if (k < t2) { t3 = t2; t2 = k; }
  else if (k < t3) { t3 = k; }
}

// ---------------- k1: z -> Xhi bf16 [n][c] + exact-numpy x2 (R2-proven) ----------------
__global__ __launch_bounds__(256) void splitz_x2_kernel(
    const float* __restrict__ z, unsigned short* __restrict__ Xhi,
    float* __restrict__ x2g) {
  __shared__ float xs[32 * 260];
  int tid = threadIdx.x;
  int n0 = blockIdx.x * 32;
  int b = n0 >> 10;
  int hw0 = n0 & 1023;
  const float* zb = z + (size_t)b * (CD * HWSZ) + hw0;
  {
    int r = tid & 31;
    int cbase = tid >> 5;
    for (int it = 0; it < 32; ++it) {
      int c = cbase + it * 8;
      xs[r * 260 + c] = zb[(size_t)c * HWSZ + r];
    }
  }
  __syncthreads();
  if (tid < 32) {
#pragma clang fp contract(off)
    const float* xr = &xs[tid * 260];
    float r0[8], r1[8];
#pragma unroll
    for (int j = 0; j < 8; ++j) {
      float v = xr[j];       r0[j] = v * v;
      float w = xr[128 + j]; r1[j] = w * w;
    }
    for (int i = 8; i < 128; i += 8) {
#pragma unroll
      for (int j = 0; j < 8; ++j) {
        float v = xr[i + j];       float a  = v * v; r0[j] = r0[j] + a;
        float w = xr[128 + i + j]; float b2 = w * w; r1[j] = r1[j] + b2;
      }
    }
    float lo = ((r0[0] + r0[1]) + (r0[2] + r0[3])) + ((r0[4] + r0[5]) + (r0[6] + r0[7]));
    float hi = ((r1[0] + r1[1]) + (r1[2] + r1[3])) + ((r1[4] + r1[5]) + (r1[6] + r1[7]));
    x2g[n0 + tid] = lo + hi;
  }
  for (int r = 0; r < 32; ++r) {
    float v = xs[r * 260 + tid];
    __hip_bfloat16 h = __float2bfloat16(v);
    Xhi[(size_t)(n0 + r) * CD + tid] = *(unsigned short*)&h;
  }
}

// ---------------- k2: emb -> Ehi bf16 [k][c] ----------------
__global__ __launch_bounds__(256) void splite_kernel(
    const float* __restrict__ emb, unsigned short* __restrict__ Ehi) {
  int n = blockIdx.x * 256 + threadIdx.x;
  __hip_bfloat16 h = __float2bfloat16(emb[n]);
  Ehi[n] = *(unsigned short*)&h;
}

// ---------------- k3: bf16 MFMA GEMM, per-(row, 128-code-block) top-3 ----------------
// Reg-staged global->LDS (R5's global_load_lds was the 0.067 TF poison),
// swizzled LDS chunk layout (slot = (chunk + (row>>1))&3 on BOTH write & read),
// XCD-swizzled flat block index.
__global__ __launch_bounds__(256) void gemm_top3_kernel(
    const unsigned short* __restrict__ Eg,   // A [8192][256] bf16
    const unsigned short* __restrict__ Xg,   // B [8192][256] bf16
    u64* __restrict__ pK1, u64* __restrict__ pK2, u64* __restrict__ pK3) {
  __shared__ unsigned short As[128 * BK];   // 8 KB [row][k], swizzled chunks
  __shared__ unsigned short Bs[128 * BK];   // 8 KB
  __shared__ u64 redK[2][128][3];           // 6 KB

  int tid = threadIdx.x;
  int bid = blockIdx.x;                         // 0..4095
  int swz = (bid & 7) * 512 + (bid >> 3);       // XCD swizzle (4096 %8==0, bijective)
  int cbx = swz & 63, rby = swz >> 6;
  int cb0 = cbx * 128;   // code tile
  int rb0 = rby * 128;   // zrow tile
  int wid = tid >> 6, lane = tid & 63;
  int llo = lane & 15, lhi = lane >> 4;
  int wr = wid & 1, wc = wid >> 1;

  f32x4 acc[4][4];
#pragma unroll
  for (int i = 0; i < 4; ++i)
#pragma unroll
    for (int j = 0; j < 4; ++j) acc[i][j] = (f32x4){0.f, 0.f, 0.f, 0.f};

  // staging: thread covers rows (tid>>2) and (tid>>2)+64, 16B chunk (tid&3)
  int srow = tid >> 2;
  const char* gA = (const char*)Eg + ((size_t)(cb0 + srow)) * 512 + (tid & 3) * 16;
  const char* gB = (const char*)Xg + ((size_t)(rb0 + srow)) * 512 + (tid & 3) * 16;
  // swizzled LDS write offset: slot = (chunk + (row>>1)) & 3; same formula row+64
  int wo = srow * 64 + (((tid & 3) + (srow >> 1)) & 3) * 16;

  // prologue: load tile 0 into regs
  float4 ra0 = *(const float4*)(gA);
  float4 ra1 = *(const float4*)(gA + (size_t)64 * 512);
  float4 rb0v = *(const float4*)(gB);
  float4 rb1 = *(const float4*)(gB + (size_t)64 * 512);

  for (int ks = 0; ks < NKSTEP; ++ks) {
    if (ks) __syncthreads();          // prev frag reads done before overwrite
    *(float4*)((char*)As + wo)        = ra0;
    *(float4*)((char*)As + 4096 + wo) = ra1;
    *(float4*)((char*)Bs + wo)        = rb0v;
    *(float4*)((char*)Bs + 4096 + wo) = rb1;
    if (ks < NKSTEP - 1) {            // prefetch next k-slab (latency hides under MFMA)
      int kb = (ks + 1) * 64;
      ra0 = *(const float4*)(gA + kb);
      ra1 = *(const float4*)(gA + (size_t)64 * 512 + kb);
      rb0v = *(const float4*)(gB + kb);
      rb1 = *(const float4*)(gB + (size_t)64 * 512 + kb);
    }
    __syncthreads();                  // tile ready

    short8 af[4], bf[4];
#pragma unroll
    for (int i = 0; i < 4; ++i) {
      int rowA = 64 * wr + 16 * i + llo;
      af[i] = *(const short8*)((const char*)As + rowA * 64 + ((lhi + (rowA >> 1)) & 3) * 16);
    }
#pragma unroll
    for (int j = 0; j < 4; ++j) {
      int rowB = 64 * wc + 16 * j + llo;
      bf[j] = *(const short8*)((const char*)Bs + rowB * 64 + ((lhi + (rowB >> 1)) & 3) * 16);
    }
#pragma unroll
    for (int i = 0; i < 4; ++i)
#pragma unroll
      for (int j = 0; j < 4; ++j)
        acc[i][j] = __builtin_amdgcn_mfma_f32_16x16x32_bf16(af[i], bf[j], acc[i][j], 0, 0, 0);
  }

  // epilogue: v = -2*dot (x2 cancels per-row; monotone), top-3 per row. (R5-validated)
  // C/D: col(zrow)=lane&15, row(code)=4*lhi+r4 (m89-verified)
#pragma unroll
  for (int j = 0; j < 4; ++j) {
    u64 t1 = ~0ull, t2 = ~0ull, t3 = ~0ull;
#pragma unroll
    for (int i = 0; i < 4; ++i)
#pragma unroll
      for (int r4 = 0; r4 < 4; ++r4) {
        float v = -2.0f * acc[i][j][r4];
        int code = cb0 + 64 * wr + 16 * i + 4 * lhi + r4;
        ins3(makeKey(v, code), t1, t2, t3);
      }
#pragma unroll
    for (int off = 16; off < 64; off <<= 1) {
      u64 o1 = __shfl_xor(t1, off, 64);
      u64 o2 = __shfl_xor(t2, off, 64);
      u64 o3 = __shfl_xor(t3, off, 64);
      ins3(o1, t1, t2, t3); ins3(o2, t1, t2, t3); ins3(o3, t1, t2, t3);
    }
    if (lhi == 0) {
      int zl = 64 * wc + 16 * j + llo;
      redK[wr][zl][0] = t1; redK[wr][zl][1] = t2; redK[wr][zl][2] = t3;
    }
  }
  __syncthreads();
  if (tid < 128) {
    u64 t1 = redK[0][tid][0], t2 = redK[0][tid][1], t3 = redK[0][tid][2];
    ins3(redK[1][tid][0], t1, t2, t3);
    ins3(redK[1][tid][1], t1, t2, t3);
    ins3(redK[1][tid][2], t1, t2, t3);
    size_t o = (size_t)cbx * NROW + rb0 + tid;
    pK1[o] = t1; pK2[o] = t2; pK3[o] = t3;
  }
}

// ---------------- k4: merge blocks + exact re-rank (R2 semantics, R5-validated) ----------------
__global__ __launch_bounds__(256) void merge_rerank_kernel(
    const float* __restrict__ z, const float* __restrict__ emb,
    const u64* __restrict__ pK1, const u64* __restrict__ pK2,
    const u64* __restrict__ pK3, const float* __restrict__ x2g,
    int* __restrict__ idx, float* __restrict__ out) {
  int n = blockIdx.x * 256 + threadIdx.x;
  u64 kmin = ~0ull;
  for (int blk = 0; blk < NBLK; ++blk) {
    u64 k = pK1[(size_t)blk * NROW + n];
    if (k < kmin) kmin = k;
  }
  float vcut = keyVal(kmin) + MARGIN;
  int cand[8]; int nc = 0;
  for (int blk = 0; blk < NBLK; ++blk) {
    size_t o = (size_t)blk * NROW + n;
    u64 k1 = pK1[o], k2 = pK2[o], k3 = pK3[o];
    if (keyVal(k1) <= vcut && nc < 8) cand[nc++] = (int)(k1 & 0xffffffffu);
    if (keyVal(k2) <= vcut && nc < 8) cand[nc++] = (int)(k2 & 0xffffffffu);
    if (keyVal(k3) <= vcut && nc < 8) cand[nc++] = (int)(k3 & 0xffffffffu);
  }
  int b = n >> 10, hw = n & 1023;
  const float* zp = z + (size_t)b * (CD * HWSZ) + hw;
  float x2 = x2g[n];
  float bs = INFINITY; int bi = 0x7fffffff;
  for (int c0 = 0; c0 < nc; ++c0) {
    int k = cand[c0];
    const float* ep = emb + (size_t)k * CD;
    float acc = 0.f;
    for (int c = 0; c < CD; ++c)                 // sequential fmaf chain == R2 dot
      acc = fmaf(zp[(size_t)c * HWSZ], ep[c], acc);
    float s = fmaf(-2.f, acc, x2);               // single rounding == np grid
    if (s < bs || (s == bs && k < bi)) { bs = s; bi = k; }
  }
  idx[n] = bi;
  out[QOFF + 1 + n] = (float)bi;
}

// ---------------- k5: gather quantized + loss partials (R2-proven) ----------------
__global__ __launch_bounds__(256) void gather_kernel(
    const float* __restrict__ z, const float* __restrict__ emb,
    const int* __restrict__ idx, float* __restrict__ out,
    float* __restrict__ lossPart) {
  __shared__ int sidx[64];
  __shared__ float swsum[4];
  int tid = threadIdx.x;
  int bid = blockIdx.x;
  int n0 = bid * 64;
  if (tid < 64) sidx[tid] = idx[n0 + tid];
  __syncthreads();
  int lane = tid & 63;
  int cw = tid >> 6;
  int b = n0 >> 10;
  int hw = (n0 & 1023) + lane;
  const float* erow = emb + (size_t)sidx[lane] * CD;
  float lacc = 0.f;
  for (int ci = 0; ci < 64; ++ci) {
    int c = cw * 64 + ci;
    float q = erow[c];
    size_t o = (size_t)b * (CD * HWSZ) + (size_t)c * HWSZ + hw;
    float zv = z[o];
    out[o] = q;
    float d = q - zv;
    lacc += d * d;
  }
#pragma unroll
  for (int off = 32; off > 0; off >>= 1) lacc += __shfl_down(lacc, off, 64);
  if (lane == 0) swsum[cw] = lacc;
  __syncthreads();
  if (tid == 0) lossPart[bid] = swsum[0] + swsum[1] + swsum[2] + swsum[3];
}

__global__ void loss_kernel(const float* __restrict__ lossPart, float* __restrict__ out) {
  if (threadIdx.x == 0) {
    double s = 0.0;
    for (int i = 0; i < 128; ++i) s += (double)lossPart[i];
    out[QOFF] = (float)(s * 1.25 / (double)(NROW * CD));
  }
}

extern "C" void kernel_launch(void* const* d_in, const int* in_sizes, int n_in,
                              void* d_out, int out_size, void* d_ws, size_t ws_size,
                              hipStream_t stream) {
  const float* z   = (const float*)d_in[0];
  const float* emb = (const float*)d_in[1];
  float* out = (float*)d_out;

  // bf16 operands live in d_out's 8MB quantized region (overwritten by gather later)
  unsigned short* Ehi = (unsigned short*)d_out;                       // 4 MB
  unsigned short* Xhi = (unsigned short*)d_out + (size_t)KCODE * CD;  // 4 MB

  // ws: pK1|pK2|pK3 (3 x 4 MB) | x2 | idx | lossPart  -> ~12.07 MB total
  u64* pK1 = (u64*)d_ws;
  u64* pK2 = pK1 + (size_t)NBLK * NROW;
  u64* pK3 = pK2 + (size_t)NBLK * NROW;
  float* x2g = (float*)(pK3 + (size_t)NBLK * NROW);
  int* idx = (int*)(x2g + NROW);
  float* lossPart = (float*)(idx + NROW);

  hipLaunchKernelGGL(splitz_x2_kernel, dim3(NROW / 32), dim3(256), 0, stream, z, Xhi, x2g);
  hipLaunchKernelGGL(splite_kernel, dim3((KCODE * CD) / 256), dim3(256), 0, stream, emb, Ehi);
  hipLaunchKernelGGL(gemm_top3_kernel, dim3((KCODE / 128) * (NROW / 128)), dim3(256), 0, stream,
                     Ehi, Xhi, pK1, pK2, pK3);
  hipLaunchKernelGGL(merge_rerank_kernel, dim3(NROW / 256), dim3(256), 0, stream,
                     z, emb, pK1, pK2, pK3, x2g, idx, out);
  hipLaunchKernelGGL(gather_kernel, dim3(NROW / 64), dim3(256), 0, stream,
                     z, emb, idx, out, lossPart);
  hipLaunchKernelGGL(loss_kernel, dim3(1), dim3(64), 0, stream, lossPart, out);
}